// Round 9
// baseline (655.690 us; speedup 1.0000x reference)
//
#include <hip/hip_runtime.h>

// EGNN layer, round 9: node_k reverted to R3 inner loop (proven 83us form)
// but 4 nodes per 256-thread block (wave per node) to escape the 16-wg/CU
// single-wave-workgroup occupancy cap. zero+prep merged. mlp2 resid bf16.
// B=4, N=16384, E=65536, DH=128, DM=64.  NB = 65536 global nodes.

typedef unsigned short ushort_t;
typedef __attribute__((ext_vector_type(8))) short bf16x8;
typedef __attribute__((ext_vector_type(4))) float f32x4;

__device__ __forceinline__ float fast_rcp(float v) { return __builtin_amdgcn_rcpf(v); }
__device__ __forceinline__ float fast_silu(float v) { return v * fast_rcp(1.0f + __expf(-v)); }
__device__ __forceinline__ ushort_t f2bf(float f) {
    unsigned u = __float_as_uint(f);
    u += 0x7fffu + ((u >> 16) & 1u);
    return (ushort_t)(u >> 16);
}
__device__ __forceinline__ float bf2f(ushort_t b) {
    return __uint_as_float(((unsigned)b) << 16);
}

// ---------------------------------------------------------------------------
// init: cursor[65536] = 0, then weight transposes (bf16 k-contiguous rows).
// grid 496 x 256 = 126976 threads; g<65536 -> cursor, else prep (61440 slots).
// ---------------------------------------------------------------------------
__global__ __launch_bounds__(256) void init_k(const float* __restrict__ pe_w1,
                                              const float* __restrict__ pe_w2,
                                              const float* __restrict__ ph_w1,
                                              const float* __restrict__ ph_w2,
                                              int* __restrict__ cursor,
                                              ushort_t* __restrict__ W1t,
                                              ushort_t* __restrict__ Wp1t,
                                              ushort_t* __restrict__ Wp2t,
                                              float* __restrict__ w2t) {
    int gg = blockIdx.x * 256 + threadIdx.x;
    if (gg < 65536) {
        cursor[gg] = 0;
        return;
    }
    int g = gg - 65536;
    if (g < 16384) {
        int c = g >> 7, k = g & 127;
        float v = (c < 64) ? pe_w1[k * 64 + c] : pe_w1[(128 + k) * 64 + (c - 64)];
        W1t[g] = f2bf(v);
    } else if (g < 16384 + 24576) {
        int g2 = g - 16384;
        int n = g2 / 192, k = g2 - n * 192;
        Wp1t[g2] = f2bf(ph_w1[k * 128 + n]);
    } else if (g < 16384 + 24576 + 16384) {
        int g3 = g - 40960;
        int n = g3 >> 7, k = g3 & 127;
        Wp2t[g3] = f2bf(ph_w2[k * 128 + n]);
    } else if (g < 16384 + 24576 + 16384 + 4096) {
        int g4 = g - 57344;
        int c = g4 >> 6, k = g4 & 63;
        w2t[g4] = pe_w2[k * 64 + c];
    }
}

// ---------------------------------------------------------------------------
// scatter: elist[gi*64 + slot] = gj  (deg max ~20 << 64)
// ---------------------------------------------------------------------------
__global__ __launch_bounds__(256) void scatter_k(const int* __restrict__ ei,
                                                 int* __restrict__ cursor,
                                                 int* __restrict__ elist) {
    int e = blockIdx.x * 256 + threadIdx.x;
    int2 sd = ((const int2*)ei)[e];
    int b = e >> 16;
    int gi = (b << 14) + sd.x;
    int gj = (b << 14) + sd.y;
    int slot = atomicAdd(&cursor[gi], 1);
    if (slot < 64) elist[gi * 64 + slot] = gj;
}

// ---------------------------------------------------------------------------
// node kernel: 4 nodes per 256-thread block, one wave per node, lane=feature.
// Inner loop identical to the proven R3 form (indexed w2c, L1-hot reloads).
// wave_barrier-only LDS broadcast (no __syncthreads: waves have divergent deg).
// ---------------------------------------------------------------------------
__global__ __launch_bounds__(256, 8) void node_k(const float* __restrict__ x,
                                                 const ushort_t* __restrict__ P,
                                                 const int* __restrict__ cursor,
                                                 const int* __restrict__ elist,
                                                 const float* __restrict__ w1,
                                                 const float* __restrict__ b1,
                                                 const float* __restrict__ w2,
                                                 const float* __restrict__ b2,
                                                 const float* __restrict__ pxw,
                                                 ushort_t* __restrict__ dh,
                                                 float* __restrict__ outx) {
    const int wid = threadIdx.x >> 6;
    const int lane = threadIdx.x & 63;
    const int n = blockIdx.x * 4 + wid;          // 0..65535
    __shared__ float m_lds[4][64];
    float* mrow = m_lds[wid];

    float w2c[64];                               // w2[:,lane] — coalesced, L1-hot
#pragma unroll
    for (int k = 0; k < 64; k++) w2c[k] = w2[k * 64 + lane];

    const float w1r = w1[256 * 64 + lane];       // dist2 row of pe_w1
    const float b1v = b1[lane];
    const float b2v = b2[lane];
    const float pxv = pxw[lane];
    const float Pi = bf2f(P[(size_t)n * 128 + lane]);
    const float xi0 = x[n * 3 + 0];
    const float xi1 = x[n * 3 + 1];
    const float xi2 = x[n * 3 + 2];

    float dhacc = 0.0f;
    float dxp0 = 0.0f, dxp1 = 0.0f, dxp2 = 0.0f;
    const int dg = min(cursor[n], 64);
    const int base = n * 64;

    for (int t = 0; t < dg; t++) {
        int gj = elist[base + t];                            // wave-uniform
        float Pj = bf2f(P[(size_t)gj * 128 + 64 + lane]);    // 128B/wave gather
        float ddx = xi0 - x[gj * 3 + 0];
        float ddy = xi1 - x[gj * 3 + 1];
        float ddz = xi2 - x[gj * 3 + 2];
        float d2 = fmaxf(ddx * ddx + ddy * ddy + ddz * ddz, 1e-12f);
        float m = fast_silu(Pi + Pj + d2 * w1r + b1v);
        __builtin_amdgcn_wave_barrier();
        mrow[lane] = m;
        __builtin_amdgcn_wave_barrier();
        float s = b2v;
#pragma unroll
        for (int k = 0; k < 64; k += 4) {
            float4 mv = *(const float4*)&mrow[k];            // broadcast read
            s = fmaf(mv.x, w2c[k + 0], s);
            s = fmaf(mv.y, w2c[k + 1], s);
            s = fmaf(mv.z, w2c[k + 2], s);
            s = fmaf(mv.w, w2c[k + 3], s);
        }
        __builtin_amdgcn_wave_barrier();
        float m2 = fast_silu(s);
        dhacc += m2;
        float c = m2 * pxv * fast_rcp(sqrtf(d2) + 1e-8f);
        dxp0 = fmaf(c, ddx, dxp0);
        dxp1 = fmaf(c, ddy, dxp1);
        dxp2 = fmaf(c, ddz, dxp2);
    }

    dh[(size_t)n * 64 + lane] = f2bf(dhacc);                 // coalesced

    for (int off = 32; off; off >>= 1) {
        dxp0 += __shfl_down(dxp0, off);
        dxp1 += __shfl_down(dxp1, off);
        dxp2 += __shfl_down(dxp2, off);
    }
    if (lane == 0) {
        outx[n * 3 + 0] = xi0 + dxp0;
        outx[n * 3 + 1] = xi1 + dxp1;
        outx[n * 3 + 2] = xi2 + dxp2;
    }
}

// ---------------------------------------------------------------------------
// bf16 MFMA GEMM with pre-transposed bf16 weights Wt[n][k] (row stride LDW).
// AMODE: 0 = fp32 A0 (cvt; optional hb emit), 1 = bf16 A0 (ld 128),
//        2 = bf16 A0 (ld 128) + bf16 A1 (ld 64, k>=128),
//        3 = fp32 A0 (ld 128) + bf16 A1 (ld 64, k>=128)   [fallback]
// ---------------------------------------------------------------------------
template <int KTOT, int LDW, int AMODE, bool DO_SILU, bool HAS_BIAS,
          bool HAS_RESID, bool RESID_BF16, bool OUT_BF16, bool EMIT_BF16>
__global__ __launch_bounds__(256, 2) void mgemm_k(const void* __restrict__ A0v,
                                                  const ushort_t* __restrict__ A1,
                                                  const ushort_t* __restrict__ Wt,
                                                  const float* __restrict__ bias,
                                                  const void* __restrict__ resid,
                                                  void* __restrict__ outv,
                                                  ushort_t* __restrict__ hbout) {
    constexpr int KPAD = 40;
    __shared__ ushort_t As[128 * KPAD];
    __shared__ ushort_t Bs[128 * KPAD];
    const int tid = threadIdx.x;
    const int m0 = blockIdx.x * 128;
    const int wave = tid >> 6;
    const int lane = tid & 63;
    const int lr = lane & 15;
    const int lq = lane >> 4;

    f32x4 acc[2][8];
#pragma unroll
    for (int mt = 0; mt < 2; mt++)
#pragma unroll
        for (int nt = 0; nt < 8; nt++) {
            f32x4 z = {0.f, 0.f, 0.f, 0.f};
            acc[mt][nt] = z;
        }

    for (int k0 = 0; k0 < KTOT; k0 += 32) {
        if (AMODE == 1 || AMODE == 2) {
            // all-bf16 A staging: straight uint4 copies
#pragma unroll
            for (int i = 0; i < 2; i++) {
                int lin = tid + i * 256;     // 0..511
                int m = lin >> 2;            // 0..127
                int kq = (lin & 3) * 8;      // 0,8,16,24
                const ushort_t* src;
                if (AMODE == 2 && k0 >= 128)
                    src = A1 + (size_t)(m0 + m) * 64 + (k0 - 128 + kq);
                else
                    src = (const ushort_t*)A0v + (size_t)(m0 + m) * 128 + k0 + kq;
                *(uint4*)&As[m * KPAD + kq] = *(const uint4*)src;
            }
        } else {
#pragma unroll
            for (int i = 0; i < 4; i++) {
                int lin = tid + i * 256;     // 0..1023
                int m = lin >> 3;            // 0..127
                int kq = (lin & 7) * 4;      // 0..28
                ushort4 w4;
                if (AMODE == 3 && k0 >= 128) {
                    w4 = *(const ushort4*)(A1 + (size_t)(m0 + m) * 64 + (k0 - 128 + kq));
                } else {
                    float4 v = *(const float4*)((const float*)A0v + (size_t)(m0 + m) * 128 + k0 + kq);
                    w4.x = f2bf(v.x); w4.y = f2bf(v.y); w4.z = f2bf(v.z); w4.w = f2bf(v.w);
                    if (EMIT_BF16)
                        *(ushort4*)(hbout + (size_t)(m0 + m) * 128 + k0 + kq) = w4;
                }
                *(ushort4*)&As[m * KPAD + kq] = w4;
            }
        }
        // stage B tile: straight bf16 copy from Wt
#pragma unroll
        for (int i = 0; i < 2; i++) {
            int lin = tid + i * 256;
            int n = lin >> 2;
            int kq = (lin & 3) * 8;
            *(uint4*)&Bs[n * KPAD + kq] =
                *(const uint4*)(Wt + (size_t)n * LDW + k0 + kq);
        }
        __syncthreads();

        bf16x8 af[2], bfr[8];
#pragma unroll
        for (int mt = 0; mt < 2; mt++) {
            int row = wave * 32 + mt * 16 + lr;
            af[mt] = *(const bf16x8*)&As[row * KPAD + lq * 8];
        }
#pragma unroll
        for (int nt = 0; nt < 8; nt++) {
            int nn = nt * 16 + lr;
            bfr[nt] = *(const bf16x8*)&Bs[nn * KPAD + lq * 8];
        }
#pragma unroll
        for (int mt = 0; mt < 2; mt++)
#pragma unroll
            for (int nt = 0; nt < 8; nt++)
                acc[mt][nt] = __builtin_amdgcn_mfma_f32_16x16x32_bf16(
                    af[mt], bfr[nt], acc[mt][nt], 0, 0, 0);
        __syncthreads();
    }

    // epilogue
#pragma unroll
    for (int mt = 0; mt < 2; mt++) {
#pragma unroll
        for (int nt = 0; nt < 8; nt++) {
#pragma unroll
            for (int r = 0; r < 4; r++) {
                int row = m0 + wave * 32 + mt * 16 + lq * 4 + r;
                int col = nt * 16 + lr;
                float v = acc[mt][nt][r];
                if (HAS_BIAS) v += bias[col];
                if (DO_SILU) v = fast_silu(v);
                if (HAS_RESID) {
                    if (RESID_BF16)
                        v += bf2f(((const ushort_t*)resid)[(size_t)row * 128 + col]);
                    else
                        v += ((const float*)resid)[(size_t)row * 128 + col];
                }
                if (OUT_BF16)
                    ((ushort_t*)outv)[(size_t)row * 128 + col] = f2bf(v);
                else
                    ((float*)outv)[(size_t)row * 128 + col] = v;
            }
        }
    }
}

// ---------------------------------------------------------------------------
extern "C" void kernel_launch(void* const* d_in, const int* in_sizes, int n_in,
                              void* d_out, int out_size, void* d_ws, size_t ws_size,
                              hipStream_t stream) {
    const float* x     = (const float*)d_in[0];
    const float* h     = (const float*)d_in[1];
    const int*   ei    = (const int*)d_in[2];
    const float* pe_w1 = (const float*)d_in[3];
    const float* pe_b1 = (const float*)d_in[4];
    const float* pe_w2 = (const float*)d_in[5];
    const float* pe_b2 = (const float*)d_in[6];
    const float* px_w  = (const float*)d_in[7];
    const float* ph_w1 = (const float*)d_in[8];
    const float* ph_b1 = (const float*)d_in[9];
    const float* ph_w2 = (const float*)d_in[10];
    const float* ph_b2 = (const float*)d_in[11];

    float* outx = (float*)d_out;                    // 4*16384*3
    float* outh = (float*)d_out + 196608;           // 4*16384*128

    // ws layout
    ushort_t* P    = (ushort_t*)d_ws;                     // 65536*128 bf16 (reused as t)
    ushort_t* dh   = P + (size_t)65536 * 128;             // 65536*64 bf16
    int* cursor    = (int*)(dh + (size_t)65536 * 64);     // 65536 i32
    int* elist     = cursor + 65536;                      // 65536*64 i32 (16 MB)
    ushort_t* W1t  = (ushort_t*)(elist + (size_t)65536 * 64);  // 128*128 bf16
    ushort_t* Wp1t = W1t + 16384;                         // 128*192 bf16
    ushort_t* Wp2t = Wp1t + 24576;                        // 128*128 bf16
    float* w2t     = (float*)(Wp2t + 16384);              // 64*64 f32
    ushort_t* hb   = (ushort_t*)(w2t + 4096);             // 65536*128 bf16 (16 MB)
    size_t need_hb = (size_t)((char*)(hb + (size_t)65536 * 128) - (char*)d_ws);
    const bool use_hb = ws_size >= need_hb;

    init_k<<<496, 256, 0, stream>>>(pe_w1, pe_w2, ph_w1, ph_w2,
                                    cursor, W1t, Wp1t, Wp2t, w2t);
    // P = h @ [W1_top | W1_mid]  (bf16 out; emits hb = bf16(h) if space)
    if (use_hb)
        mgemm_k<128, 128, 0, false, false, false, false, true, true>
            <<<512, 256, 0, stream>>>(h, nullptr, W1t, nullptr, nullptr, P, hb);
    else
        mgemm_k<128, 128, 0, false, false, false, false, true, false>
            <<<512, 256, 0, stream>>>(h, nullptr, W1t, nullptr, nullptr, P, nullptr);
    scatter_k<<<1024, 256, 0, stream>>>(ei, cursor, elist);
    node_k<<<16384, 256, 0, stream>>>(x, P, cursor, elist,
                                      pe_w1, pe_b1, pe_w2, pe_b2, px_w,
                                      dh, outx);
    // t = silu([h | dh] @ ph_w1 + b1)  (bf16 out, overwrites P)
    if (use_hb)
        mgemm_k<192, 192, 2, true, true, false, false, true, false>
            <<<512, 256, 0, stream>>>(hb, dh, Wp1t, ph_b1, nullptr, P, nullptr);
    else
        mgemm_k<192, 192, 3, true, true, false, false, true, false>
            <<<512, 256, 0, stream>>>(h, dh, Wp1t, ph_b1, nullptr, P, nullptr);
    // out_h = h + t @ ph_w2 + b2  (fp32 out; resid bf16 from hb if available)
    if (use_hb)
        mgemm_k<128, 128, 1, false, true, true, true, false, false>
            <<<512, 256, 0, stream>>>(P, nullptr, Wp2t, ph_b2, hb, outh, nullptr);
    else
        mgemm_k<128, 128, 1, false, true, true, false, false, false>
            <<<512, 256, 0, stream>>>(P, nullptr, Wp2t, ph_b2, h, outh, nullptr);
}

// Round 10
// 193.803 us; speedup vs baseline: 3.3833x; 3.3833x over previous
//
#include <hip/hip_runtime.h>

// EGNN layer, round 10: node_k = R3 form + f16 dot2 second layer (halved L1
// traffic); mlp1+mlp2 fused with t-tile resident in LDS.
// B=4, N=16384, E=65536, DH=128, DM=64.  NB = 65536 global nodes.

typedef unsigned short ushort_t;
typedef __attribute__((ext_vector_type(8))) short bf16x8;
typedef __attribute__((ext_vector_type(4))) float f32x4;
typedef _Float16 h2 __attribute__((ext_vector_type(2)));

__device__ __forceinline__ float fast_rcp(float v) { return __builtin_amdgcn_rcpf(v); }
__device__ __forceinline__ float fast_silu(float v) { return v * fast_rcp(1.0f + __expf(-v)); }
__device__ __forceinline__ ushort_t f2bf(float f) {
    unsigned u = __float_as_uint(f);
    u += 0x7fffu + ((u >> 16) & 1u);
    return (ushort_t)(u >> 16);
}
__device__ __forceinline__ float bf2f(ushort_t b) {
    return __uint_as_float(((unsigned)b) << 16);
}
__device__ __forceinline__ h2 u2h2(unsigned u) {
    union { unsigned u; h2 h; } v; v.u = u; return v.h;
}

// ---------------------------------------------------------------------------
// init: cursor=0 (65536) + weight transforms. 488*256 = 124928 threads exact.
//  W1t  bf16[128][128] : fused pe_w1 cols, k-contiguous
//  Wp1t bf16[128][192] : ph_w1^T
//  Wp2t bf16[128][128] : ph_w2^T
//  w2h  uint[32][64]   : w2h[k2*64+c] = half2(pe_w2[2k2][c], pe_w2[2k2+1][c])
// ---------------------------------------------------------------------------
__global__ __launch_bounds__(256) void init_k(const float* __restrict__ pe_w1,
                                              const float* __restrict__ pe_w2,
                                              const float* __restrict__ ph_w1,
                                              const float* __restrict__ ph_w2,
                                              int* __restrict__ cursor,
                                              ushort_t* __restrict__ W1t,
                                              ushort_t* __restrict__ Wp1t,
                                              ushort_t* __restrict__ Wp2t,
                                              unsigned* __restrict__ w2h) {
    int gg = blockIdx.x * 256 + threadIdx.x;
    if (gg < 65536) { cursor[gg] = 0; return; }
    int g = gg - 65536;
    if (g < 16384) {
        int c = g >> 7, k = g & 127;
        float v = (c < 64) ? pe_w1[k * 64 + c] : pe_w1[(128 + k) * 64 + (c - 64)];
        W1t[g] = f2bf(v);
    } else if (g < 40960) {
        int g2 = g - 16384;
        int n = g2 / 192, k = g2 - n * 192;
        Wp1t[g2] = f2bf(ph_w1[k * 128 + n]);
    } else if (g < 57344) {
        int g3 = g - 40960;
        int n = g3 >> 7, k = g3 & 127;
        Wp2t[g3] = f2bf(ph_w2[k * 128 + n]);
    } else if (g < 59392) {
        int g4 = g - 57344;
        int k2 = g4 >> 6, c = g4 & 63;
        union { unsigned u; _Float16 h[2]; } p;
        p.h[0] = (_Float16)pe_w2[(2 * k2) * 64 + c];
        p.h[1] = (_Float16)pe_w2[(2 * k2 + 1) * 64 + c];
        w2h[g4] = p.u;
    }
}

// ---------------------------------------------------------------------------
// scatter: elist[gi*64 + slot] = gj  (deg max ~20 << 64)
// ---------------------------------------------------------------------------
__global__ __launch_bounds__(256) void scatter_k(const int* __restrict__ ei,
                                                 int* __restrict__ cursor,
                                                 int* __restrict__ elist) {
    int e = blockIdx.x * 256 + threadIdx.x;
    int2 sd = ((const int2*)ei)[e];
    int b = e >> 16;
    int gi = (b << 14) + sd.x;
    int gj = (b << 14) + sd.y;
    int slot = atomicAdd(&cursor[gi], 1);
    if (slot < 64) elist[gi * 64 + slot] = gj;
}

// ---------------------------------------------------------------------------
// node kernel: one wave per node (R3-proven structure), lane = feature.
// Second layer: 32 x v_dot2_f32_f16 against packed w2h (L1-hot, half bytes
// of the fp32 version). m broadcast through LDS as f16 bits.
// ---------------------------------------------------------------------------
__global__ __launch_bounds__(64, 4) void node_k(const float* __restrict__ x,
                                                const ushort_t* __restrict__ P,
                                                const int* __restrict__ cursor,
                                                const int* __restrict__ elist,
                                                const float* __restrict__ w1,
                                                const float* __restrict__ b1,
                                                const unsigned* __restrict__ w2h,
                                                const float* __restrict__ b2,
                                                const float* __restrict__ pxw,
                                                ushort_t* __restrict__ dh,
                                                float* __restrict__ outx) {
    const int n = blockIdx.x;
    const int lane = threadIdx.x;
    __shared__ unsigned m_u[32];                 // 64 halves
    ushort_t* mh = (ushort_t*)m_u;

    const float w1r = w1[256 * 64 + lane];       // dist2 row of pe_w1
    const float b1v = b1[lane];
    const float b2v = b2[lane];
    const float pxv = pxw[lane];
    const float Pi = bf2f(P[(size_t)n * 128 + lane]);
    const float xi0 = x[n * 3 + 0];
    const float xi1 = x[n * 3 + 1];
    const float xi2 = x[n * 3 + 2];

    float dhacc = 0.0f;
    float dxp0 = 0.0f, dxp1 = 0.0f, dxp2 = 0.0f;
    const int dg = min(cursor[n], 64);
    const int base = n * 64;

    for (int t = 0; t < dg; t++) {
        int gj = elist[base + t];                            // wave-uniform
        float Pj = bf2f(P[(size_t)gj * 128 + 64 + lane]);    // 128B/wave gather
        float ddx = xi0 - x[gj * 3 + 0];
        float ddy = xi1 - x[gj * 3 + 1];
        float ddz = xi2 - x[gj * 3 + 2];
        float d2 = fmaxf(ddx * ddx + ddy * ddy + ddz * ddz, 1e-12f);
        float m = fast_silu(Pi + Pj + d2 * w1r + b1v);
        __builtin_amdgcn_wave_barrier();
        union { ushort_t s; _Float16 h; } mc;
        mc.h = (_Float16)m;
        mh[lane] = mc.s;
        __builtin_amdgcn_wave_barrier();
        float s = b2v;
#pragma unroll
        for (int k2 = 0; k2 < 32; k2++) {
            h2 mm = u2h2(m_u[k2]);                           // LDS broadcast
            h2 ww = u2h2(w2h[k2 * 64 + lane]);               // coalesced, L1-hot
            s = __builtin_amdgcn_fdot2(mm, ww, s, false);
        }
        __builtin_amdgcn_wave_barrier();
        float m2 = fast_silu(s);
        dhacc += m2;
        float c = m2 * pxv * fast_rcp(sqrtf(d2) + 1e-8f);
        dxp0 = fmaf(c, ddx, dxp0);
        dxp1 = fmaf(c, ddy, dxp1);
        dxp2 = fmaf(c, ddz, dxp2);
    }

    dh[(size_t)n * 64 + lane] = f2bf(dhacc);                 // coalesced

    for (int off = 32; off; off >>= 1) {
        dxp0 += __shfl_down(dxp0, off);
        dxp1 += __shfl_down(dxp1, off);
        dxp2 += __shfl_down(dxp2, off);
    }
    if (lane == 0) {
        outx[n * 3 + 0] = xi0 + dxp0;
        outx[n * 3 + 1] = xi1 + dxp1;
        outx[n * 3 + 2] = xi2 + dxp2;
    }
}

// ---------------------------------------------------------------------------
// P-GEMM: P = h @ [W1_top|W1_mid] (bf16 out), optionally emits hb=bf16(h).
// 128x128 block, 4 waves, 2x8 mfma 16x16x32, KPAD=40.
// ---------------------------------------------------------------------------
template <bool EMIT_BF16>
__global__ __launch_bounds__(256, 2) void pgemm_k(const float* __restrict__ A0,
                                                  const ushort_t* __restrict__ Wt,
                                                  ushort_t* __restrict__ outP,
                                                  ushort_t* __restrict__ hbout) {
    constexpr int KPAD = 40;
    __shared__ ushort_t As[128 * KPAD];
    __shared__ ushort_t Bs[128 * KPAD];
    const int tid = threadIdx.x;
    const int m0 = blockIdx.x * 128;
    const int wave = tid >> 6;
    const int lane = tid & 63;
    const int lr = lane & 15;
    const int lq = lane >> 4;

    f32x4 acc[2][8];
#pragma unroll
    for (int mt = 0; mt < 2; mt++)
#pragma unroll
        for (int nt = 0; nt < 8; nt++) { f32x4 z = {0.f,0.f,0.f,0.f}; acc[mt][nt] = z; }

    for (int k0 = 0; k0 < 128; k0 += 32) {
#pragma unroll
        for (int i = 0; i < 4; i++) {
            int lin = tid + i * 256;
            int m = lin >> 3;
            int kq = (lin & 7) * 4;
            float4 v = *(const float4*)(A0 + (size_t)(m0 + m) * 128 + k0 + kq);
            ushort4 w4;
            w4.x = f2bf(v.x); w4.y = f2bf(v.y); w4.z = f2bf(v.z); w4.w = f2bf(v.w);
            if (EMIT_BF16)
                *(ushort4*)(hbout + (size_t)(m0 + m) * 128 + k0 + kq) = w4;
            *(ushort4*)&As[m * KPAD + kq] = w4;
        }
#pragma unroll
        for (int i = 0; i < 2; i++) {
            int lin = tid + i * 256;
            int n = lin >> 2;
            int kq = (lin & 3) * 8;
            *(uint4*)&Bs[n * KPAD + kq] = *(const uint4*)(Wt + (size_t)n * 128 + k0 + kq);
        }
        __syncthreads();
        bf16x8 af[2], bfr[8];
#pragma unroll
        for (int mt = 0; mt < 2; mt++)
            af[mt] = *(const bf16x8*)&As[(wave * 32 + mt * 16 + lr) * KPAD + lq * 8];
#pragma unroll
        for (int nt = 0; nt < 8; nt++)
            bfr[nt] = *(const bf16x8*)&Bs[(nt * 16 + lr) * KPAD + lq * 8];
#pragma unroll
        for (int mt = 0; mt < 2; mt++)
#pragma unroll
            for (int nt = 0; nt < 8; nt++)
                acc[mt][nt] = __builtin_amdgcn_mfma_f32_16x16x32_bf16(af[mt], bfr[nt], acc[mt][nt], 0, 0, 0);
        __syncthreads();
    }
#pragma unroll
    for (int mt = 0; mt < 2; mt++)
#pragma unroll
        for (int nt = 0; nt < 8; nt++)
#pragma unroll
            for (int r = 0; r < 4; r++) {
                int row = m0 + wave * 32 + mt * 16 + lq * 4 + r;
                int col = nt * 16 + lr;
                outP[(size_t)row * 128 + col] = f2bf(acc[mt][nt][r]);
            }
}

// ---------------------------------------------------------------------------
// Fused node MLP: out_h = h + silu([h|dh]@W1 + b1) @ W2 + b2.
// Phase 1: t(128x128) = silu([h|dh]@W1+b1) -> LDS (bf16, pad 136).
// Phase 2: out = t @ W2 + b2 + h, straight from LDS. No t round-trip to HBM.
// ---------------------------------------------------------------------------
template <bool USE_HB>
__global__ __launch_bounds__(256, 2) void mlp_fused_k(const float* __restrict__ h,
                                                      const ushort_t* __restrict__ hb,
                                                      const ushort_t* __restrict__ dh,
                                                      const ushort_t* __restrict__ Wp1t,
                                                      const float* __restrict__ b1,
                                                      const ushort_t* __restrict__ Wp2t,
                                                      const float* __restrict__ b2,
                                                      float* __restrict__ outh) {
    constexpr int KPAD = 40, TPAD = 136;
    __shared__ ushort_t As[128 * KPAD];
    __shared__ ushort_t Bs[128 * KPAD];
    __shared__ ushort_t Ts[128 * TPAD];
    const int tid = threadIdx.x;
    const int m0 = blockIdx.x * 128;
    const int wave = tid >> 6;
    const int lane = tid & 63;
    const int lr = lane & 15;
    const int lq = lane >> 4;

    f32x4 acc[2][8];
#pragma unroll
    for (int mt = 0; mt < 2; mt++)
#pragma unroll
        for (int nt = 0; nt < 8; nt++) { f32x4 z = {0.f,0.f,0.f,0.f}; acc[mt][nt] = z; }

    // ---- phase 1: t = silu([h|dh] @ W1 + b1), K = 192
    for (int k0 = 0; k0 < 192; k0 += 32) {
        if (USE_HB) {
#pragma unroll
            for (int i = 0; i < 2; i++) {
                int lin = tid + i * 256;
                int m = lin >> 2;
                int kq = (lin & 3) * 8;
                const ushort_t* src = (k0 >= 128)
                    ? dh + (size_t)(m0 + m) * 64 + (k0 - 128 + kq)
                    : hb + (size_t)(m0 + m) * 128 + k0 + kq;
                *(uint4*)&As[m * KPAD + kq] = *(const uint4*)src;
            }
        } else {
#pragma unroll
            for (int i = 0; i < 4; i++) {
                int lin = tid + i * 256;
                int m = lin >> 3;
                int kq = (lin & 7) * 4;
                ushort4 w4;
                if (k0 >= 128) {
                    w4 = *(const ushort4*)(dh + (size_t)(m0 + m) * 64 + (k0 - 128 + kq));
                } else {
                    float4 v = *(const float4*)(h + (size_t)(m0 + m) * 128 + k0 + kq);
                    w4.x = f2bf(v.x); w4.y = f2bf(v.y); w4.z = f2bf(v.z); w4.w = f2bf(v.w);
                }
                *(ushort4*)&As[m * KPAD + kq] = w4;
            }
        }
#pragma unroll
        for (int i = 0; i < 2; i++) {
            int lin = tid + i * 256;
            int n = lin >> 2;
            int kq = (lin & 3) * 8;
            *(uint4*)&Bs[n * KPAD + kq] = *(const uint4*)(Wp1t + (size_t)n * 192 + k0 + kq);
        }
        __syncthreads();
        bf16x8 af[2], bfr[8];
#pragma unroll
        for (int mt = 0; mt < 2; mt++)
            af[mt] = *(const bf16x8*)&As[(wave * 32 + mt * 16 + lr) * KPAD + lq * 8];
#pragma unroll
        for (int nt = 0; nt < 8; nt++)
            bfr[nt] = *(const bf16x8*)&Bs[(nt * 16 + lr) * KPAD + lq * 8];
#pragma unroll
        for (int mt = 0; mt < 2; mt++)
#pragma unroll
            for (int nt = 0; nt < 8; nt++)
                acc[mt][nt] = __builtin_amdgcn_mfma_f32_16x16x32_bf16(af[mt], bfr[nt], acc[mt][nt], 0, 0, 0);
        __syncthreads();
    }
    // epilogue 1: silu -> Ts (bf16)
#pragma unroll
    for (int mt = 0; mt < 2; mt++)
#pragma unroll
        for (int nt = 0; nt < 8; nt++)
#pragma unroll
            for (int r = 0; r < 4; r++) {
                int row = wave * 32 + mt * 16 + lq * 4 + r;
                int col = nt * 16 + lr;
                Ts[row * TPAD + col] = f2bf(fast_silu(acc[mt][nt][r] + b1[col]));
            }
    __syncthreads();

    // ---- phase 2: out = t @ W2 + b2 + h, K = 128, A from Ts
    f32x4 acc2[2][8];
#pragma unroll
    for (int mt = 0; mt < 2; mt++)
#pragma unroll
        for (int nt = 0; nt < 8; nt++) { f32x4 z = {0.f,0.f,0.f,0.f}; acc2[mt][nt] = z; }

    for (int k0 = 0; k0 < 128; k0 += 32) {
#pragma unroll
        for (int i = 0; i < 2; i++) {
            int lin = tid + i * 256;
            int n = lin >> 2;
            int kq = (lin & 3) * 8;
            *(uint4*)&Bs[n * KPAD + kq] = *(const uint4*)(Wp2t + (size_t)n * 128 + k0 + kq);
        }
        __syncthreads();
        bf16x8 af[2], bfr[8];
#pragma unroll
        for (int mt = 0; mt < 2; mt++)
            af[mt] = *(const bf16x8*)&Ts[(wave * 32 + mt * 16 + lr) * TPAD + k0 + lq * 8];
#pragma unroll
        for (int nt = 0; nt < 8; nt++)
            bfr[nt] = *(const bf16x8*)&Bs[(nt * 16 + lr) * KPAD + lq * 8];
#pragma unroll
        for (int mt = 0; mt < 2; mt++)
#pragma unroll
            for (int nt = 0; nt < 8; nt++)
                acc2[mt][nt] = __builtin_amdgcn_mfma_f32_16x16x32_bf16(af[mt], bfr[nt], acc2[mt][nt], 0, 0, 0);
        __syncthreads();
    }
    // epilogue 2: + b2 + h residual
#pragma unroll
    for (int mt = 0; mt < 2; mt++)
#pragma unroll
        for (int nt = 0; nt < 8; nt++)
#pragma unroll
            for (int r = 0; r < 4; r++) {
                int row = m0 + wave * 32 + mt * 16 + lq * 4 + r;
                int col = nt * 16 + lr;
                float v = acc2[mt][nt][r] + b2[col];
                if (USE_HB) v += bf2f(hb[(size_t)row * 128 + col]);
                else        v += h[(size_t)row * 128 + col];
                outh[(size_t)row * 128 + col] = v;
            }
}

// ---------------------------------------------------------------------------
extern "C" void kernel_launch(void* const* d_in, const int* in_sizes, int n_in,
                              void* d_out, int out_size, void* d_ws, size_t ws_size,
                              hipStream_t stream) {
    const float* x     = (const float*)d_in[0];
    const float* h     = (const float*)d_in[1];
    const int*   ei    = (const int*)d_in[2];
    const float* pe_w1 = (const float*)d_in[3];
    const float* pe_b1 = (const float*)d_in[4];
    const float* pe_w2 = (const float*)d_in[5];
    const float* pe_b2 = (const float*)d_in[6];
    const float* px_w  = (const float*)d_in[7];
    const float* ph_w1 = (const float*)d_in[8];
    const float* ph_b1 = (const float*)d_in[9];
    const float* ph_w2 = (const float*)d_in[10];
    const float* ph_b2 = (const float*)d_in[11];

    float* outx = (float*)d_out;                    // 4*16384*3
    float* outh = (float*)d_out + 196608;           // 4*16384*128

    // ws layout
    ushort_t* P    = (ushort_t*)d_ws;                     // 65536*128 bf16
    ushort_t* dh   = P + (size_t)65536 * 128;             // 65536*64 bf16
    int* cursor    = (int*)(dh + (size_t)65536 * 64);     // 65536 i32
    int* elist     = cursor + 65536;                      // 65536*64 i32 (16 MB)
    ushort_t* W1t  = (ushort_t*)(elist + (size_t)65536 * 64);  // 128*128 bf16
    ushort_t* Wp1t = W1t + 16384;                         // 128*192 bf16
    ushort_t* Wp2t = Wp1t + 24576;                        // 128*128 bf16
    unsigned* w2h  = (unsigned*)(Wp2t + 16384);           // 32*64 uint (in 16KB slot)
    ushort_t* hb   = (ushort_t*)(w2h + 4096);             // 65536*128 bf16 (16 MB)
    size_t need_hb = (size_t)((char*)(hb + (size_t)65536 * 128) - (char*)d_ws);
    const bool use_hb = ws_size >= need_hb;

    init_k<<<488, 256, 0, stream>>>(pe_w1, pe_w2, ph_w1, ph_w2,
                                    cursor, W1t, Wp1t, Wp2t, w2h);
    if (use_hb)
        pgemm_k<true><<<512, 256, 0, stream>>>(h, W1t, P, hb);
    else
        pgemm_k<false><<<512, 256, 0, stream>>>(h, W1t, P, nullptr);
    scatter_k<<<1024, 256, 0, stream>>>(ei, cursor, elist);
    node_k<<<65536, 64, 0, stream>>>(x, P, cursor, elist,
                                     pe_w1, pe_b1, w2h, pe_b2, px_w,
                                     dh, outx);
    if (use_hb)
        mlp_fused_k<true><<<512, 256, 0, stream>>>(h, hb, dh, Wp1t, ph_b1,
                                                   Wp2t, ph_b2, outh);
    else
        mlp_fused_k<false><<<512, 256, 0, stream>>>(h, nullptr, dh, Wp1t, ph_b1,
                                                    Wp2t, ph_b2, outh);
}